// Round 10
// baseline (215.260 us; speedup 1.0000x reference)
//
#include <hip/hip_runtime.h>

// LiquidNet (LTC) on MI355X — register/SGPR inner loop (no LDS in part_k).
// R9 lesson: all-LDS loop is LDS-pipe bound (~30 cy per 128 elems, per-CU).
// Fix: v lives in per-lane VGPRs (vv[64], static-index full unroll);
// weights live at wave-uniform addresses -> s_load into SGPRs (free operands).
// Inner loop = pure VALU/trans. part_k has zero __shared__.
// 13 launches: prep, 6x (part, fin).

constexpr int B_ = 64;
constexpr int F_ = 256;
constexpr int H_ = 768;
constexpr int UNFOLDS_ = 6;

constexpr int LI  = 64;                     // i (or f) chunk per block
constexpr int JPB = 8;                      // j per block (4 waves x 2)
constexpr int JG  = H_ / JPB;               // 96 j-groups
constexpr int NS_STEP = H_ / LI;            // 12 slices
constexpr int NS_SENS = F_ / LI;            // 4 slices
constexpr int STEP_BLOCKS = JG * NS_STEP;   // 1152
constexpr int SENS_BLOCKS = JG * NS_SENS;   // 384
constexpr int FIN_BLOCKS  = (B_ * H_) / 256;      // 192
constexpr int TILE_STEP = (H_ / 32) * (H_ / 32);  // 576
constexpr int TILE_SENS = (F_ / 32) * (H_ / 32);  // 192
constexpr int PREP_BLOCKS = TILE_STEP + TILE_SENS + 1 + 3;

// ------------------------------------------------------------------- prep ---
__global__ __launch_bounds__(256) void prep_k(
    const float* __restrict__ sigma, const float* __restrict__ mu,
    const float* __restrict__ W, const float* __restrict__ erev,
    const float* __restrict__ ssig, const float* __restrict__ smu,
    const float* __restrict__ sW, const float* __restrict__ serev,
    const float* __restrict__ inputs, const float* __restrict__ iw,
    const float* __restrict__ ib, const float* __restrict__ state,
    float4* __restrict__ pk_step,   // [H][H] j-major: {c, -sg2, w, w*erev}
    float4* __restrict__ pk_sens,   // [H][F] j-major
    float* __restrict__ xT,         // [F][B]
    float* __restrict__ vT_init)    // [H][B]
{
    const int tid = threadIdx.x;
    const float L2E = 1.44269504088896f;
    int blk = blockIdx.x;

    if (blk < TILE_STEP + TILE_SENS) {
        const bool sens = blk >= TILE_STEP;
        if (sens) blk -= TILE_STEP;
        const int ti = blk / 24, tj = blk % 24;     // 24 j-tiles per row
        const int i0 = ti * 32, j0 = tj * 32;
        const float* A0 = sens ? ssig : sigma;
        const float* A1 = sens ? smu : mu;
        const float* A2 = sens ? sW : W;
        const float* A3 = sens ? serev : erev;
        float4* outp = sens ? pk_sens : pk_step;
        const int ILEN = sens ? F_ : H_;

        __shared__ float tsg[32][33], tmu[32][33], tw[32][33], te[32][33];
        const int col = tid & 31;
#pragma unroll
        for (int k = 0; k < 4; ++k) {
            int row = (tid >> 5) + k * 8;
            int idx = (i0 + row) * H_ + j0 + col;
            tsg[row][col] = A0[idx];
            tmu[row][col] = A1[idx];
            tw [row][col] = A2[idx];
            te [row][col] = A3[idx];
        }
        __syncthreads();
#pragma unroll
        for (int k = 0; k < 4; ++k) {
            int jj = (tid >> 5) + k * 8;
            int ii = tid & 31;
            float sg2 = tsg[ii][jj] * L2E;
            float4 v;
            v.x = sg2 * tmu[ii][jj];      // c = sg2*mu
            v.y = -sg2;
            v.z = tw[ii][jj];
            v.w = tw[ii][jj] * te[ii][jj];
            outp[(j0 + jj) * ILEN + (i0 + ii)] = v;
        }
    } else if (blk == TILE_STEP + TILE_SENS) {
        for (int e = tid; e < B_ * F_; e += 256) {
            int f = e & (F_ - 1), b = e >> 8;
            xT[f * B_ + b] = fmaf(inputs[b * F_ + f], iw[f], ib[f]);
        }
    } else {
        const int vb = blk - (TILE_STEP + TILE_SENS + 1);   // 0..2
        for (int e = tid; e < (B_ * H_) / 3; e += 256) {
            int g = vb * ((B_ * H_) / 3) + e;
            int b = g / H_, h = g % H_;
            vT_init[h * B_ + b] = state[g];
        }
    }
}

// --------------------------------------------------------------- partials ---
__global__ __launch_bounds__(256) void part_k(
    const float* __restrict__ vT,        // [H][B]
    const float4* __restrict__ pk_step,
    const float4* __restrict__ pk_sens,
    const float* __restrict__ xT,        // [F][B]
    float* __restrict__ step_part,       // [NS_STEP][2][H][B]
    float* __restrict__ sens_part)       // [NS_SENS][2][H][B]
{
    const int tid  = threadIdx.x;
    const int lane = tid & 63;
    const int wv   = __builtin_amdgcn_readfirstlane(tid >> 6);

    int sb = blockIdx.x;
    int jg, sl, ilen;
    const float4* pkb;
    const float* vsrc;
    float* pout;
    if (sb < STEP_BLOCKS) {
        jg = sb % JG; sl = sb / JG; ilen = H_;
        pkb = pk_step; vsrc = vT; pout = step_part;
    } else {
        int s = sb - STEP_BLOCKS;
        jg = s % JG; sl = s / JG; ilen = F_;
        pkb = pk_sens; vsrc = xT; pout = sens_part;
    }
    const int i0 = sl * LI, j0 = jg * JPB;
    const int j = j0 + wv * 2;

    // wave-uniform weight rows -> s_load path
    const float4* p0 = pkb + (size_t)j * ilen + i0;
    const float4* p1 = p0 + ilen;

    // v chunk into per-lane registers (static indices -> VGPRs)
    float vv[LI];
#pragma unroll
    for (int k = 0; k < LI; ++k) vv[k] = vsrc[(i0 + k) * B_ + lane];

    float n0 = 0.f, d0 = 0.f, n1 = 0.f, d1 = 0.f;
#pragma unroll
    for (int k = 0; k < LI; ++k) {
        float4 a = p0[k], b = p1[k];
        float t0 = fmaf(a.y, vv[k], a.x);
        float t1 = fmaf(b.y, vv[k], b.x);
        float s0 = __builtin_amdgcn_rcpf(1.0f + __builtin_amdgcn_exp2f(t0));
        float s1 = __builtin_amdgcn_rcpf(1.0f + __builtin_amdgcn_exp2f(t1));
        d0 = fmaf(a.z, s0, d0);  n0 = fmaf(a.w, s0, n0);
        d1 = fmaf(b.z, s1, d1);  n1 = fmaf(b.w, s1, n1);
    }

    float* pn = pout + (sl * 2 + 0) * (H_ * B_);
    float* pd = pout + (sl * 2 + 1) * (H_ * B_);
    pn[(j + 0) * B_ + lane] = n0;  pd[(j + 0) * B_ + lane] = d0;
    pn[(j + 1) * B_ + lane] = n1;  pd[(j + 1) * B_ + lane] = d1;
}

// --------------------------------------------------------------- finalize ---
__global__ __launch_bounds__(256) void fin_k(
    const float* __restrict__ v_prev,    // [H][B]
    const float* __restrict__ step_part,
    const float* __restrict__ sens_part,
    const float* __restrict__ vleak, const float* __restrict__ gleak,
    const float* __restrict__ cm,
    float* __restrict__ vT_out,          // [H][B]
    float* __restrict__ out0, float* __restrict__ out1, int last)
{
    const int e = blockIdx.x * 256 + threadIdx.x;   // over H*B
    const int b = e & 63, h = e >> 6;
    const int o = h * B_ + b;

    float n = 0.f, d = 0.f;
#pragma unroll
    for (int sl = 0; sl < NS_STEP; ++sl) {
        n += step_part[((sl * 2 + 0) * H_ + h) * B_ + b];
        d += step_part[((sl * 2 + 1) * H_ + h) * B_ + b];
    }
#pragma unroll
    for (int sl = 0; sl < NS_SENS; ++sl) {
        n += sens_part[((sl * 2 + 0) * H_ + h) * B_ + b];
        d += sens_part[((sl * 2 + 1) * H_ + h) * B_ + b];
    }

    float vp = v_prev[o];
    float g  = gleak[h];
    float numer = fmaf(cm[h], vp, fmaf(g, vleak[h], n));
    float denom = cm[h] + g + d;
    float vn = numer / denom;
    vT_out[o] = vn;
    if (last) { out0[b * H_ + h] = vn; out1[b * H_ + h] = vn; }
}

// ----------------------------------------------------------------- launch ---
extern "C" void kernel_launch(void* const* d_in, const int* in_sizes, int n_in,
                              void* d_out, int out_size, void* d_ws, size_t ws_size,
                              hipStream_t stream) {
    const float* inputs = (const float*)d_in[0];
    const float* state  = (const float*)d_in[1];
    const float* iw     = (const float*)d_in[2];
    const float* ib     = (const float*)d_in[3];
    const float* smu    = (const float*)d_in[4];
    const float* ssig   = (const float*)d_in[5];
    const float* sW     = (const float*)d_in[6];
    const float* serev  = (const float*)d_in[7];
    const float* mu     = (const float*)d_in[8];
    const float* sigma  = (const float*)d_in[9];
    const float* W      = (const float*)d_in[10];
    const float* erev   = (const float*)d_in[11];
    const float* vleak  = (const float*)d_in[12];
    const float* gleak  = (const float*)d_in[13];
    const float* cm     = (const float*)d_in[14];
    float* out = (float*)d_out;

    float* ws = (float*)d_ws;
    float4* pk_step = (float4*)ws;                            // H*H float4
    float4* pk_sens = pk_step + H_ * H_;                      // H*F float4
    float*  xT      = (float*)(pk_sens + H_ * F_);            // F*B
    float*  step_part = xT + F_ * B_;                         // NS_STEP*2*H*B
    float*  sens_part = step_part + NS_STEP * 2 * H_ * B_;    // NS_SENS*2*H*B
    float*  vinit     = sens_part + NS_SENS * 2 * H_ * B_;    // H*B
    float*  vb0       = vinit + H_ * B_;                      // H*B
    float*  vb1       = vb0 + H_ * B_;                        // H*B

    prep_k<<<PREP_BLOCKS, 256, 0, stream>>>(
        sigma, mu, W, erev, ssig, smu, sW, serev, inputs, iw, ib, state,
        pk_step, pk_sens, xT, vinit);

    const float* vsrc = vinit;
    for (int t = 0; t < UNFOLDS_; ++t) {
        const int last = (t == UNFOLDS_ - 1);
        float* vdst = (t & 1) ? vb1 : vb0;
        int nblk = (t == 0) ? (STEP_BLOCKS + SENS_BLOCKS) : STEP_BLOCKS;
        part_k<<<nblk, 256, 0, stream>>>(vsrc, pk_step, pk_sens, xT,
                                         step_part, sens_part);
        fin_k<<<FIN_BLOCKS, 256, 0, stream>>>(vsrc, step_part, sens_part,
                                              vleak, gleak, cm, vdst,
                                              out, out + B_ * H_, last);
        vsrc = vdst;
    }
}